// Round 2
// baseline (57.618 us; speedup 1.0000x reference)
//
#include <hip/hip_runtime.h>

#define W      1024
#define NROWS  16384            // 16 * 1 * 1024
#define NPIX   16777216.0       // 16 * 1024 * 1024
#define EPSF   1e-5f
#define PX     8                // pixels per lane
#define SEG    (PX * 64)        // 512 pixels per wave
#define WPR    (W / SEG)        // 2 waves per row
#define NWAVES (NROWS * WPR)    // 32768
#define NBLOCKS (NWAVES / 4)    // 8192 blocks of 4 waves

// One wave per 512-pixel row segment. No LDS, no barriers: halo comes from
// lane shuffles; segment-edge lanes patch from global (zeros at row edges).
__global__ __launch_bounds__(256) void lncc_rows(const float* __restrict__ I,
                                                 const float* __restrict__ J,
                                                 float* __restrict__ partials) {
    const int lane = threadIdx.x & 63;
    const int wid  = (blockIdx.x << 2) | (threadIdx.x >> 6);
    const int row  = wid >> 1;
    const int h    = wid & 1;            // which half of the row
    const float* rowI = I + (size_t)row * W + h * SEG;
    const float* rowJ = J + (size_t)row * W + h * SEG;

    // Own 8 pixels per array (4 coalesced float4 loads, all issued up front).
    const float4 a0 = *(const float4*)(rowI + 8 * lane);
    const float4 a1 = *(const float4*)(rowI + 8 * lane + 4);
    const float4 b0 = *(const float4*)(rowJ + 8 * lane);
    const float4 b1 = *(const float4*)(rowJ + 8 * lane + 4);

    // Segment-edge halo patches (predicated; zeros at the row boundary).
    const float4 zed = make_float4(0.f, 0.f, 0.f, 0.f);
    float4 alp = zed, blp = zed, arp = zed, brp = zed;
    if (lane == 0 && h > 0) {
        alp = *(const float4*)(rowI - 4);
        blp = *(const float4*)(rowJ - 4);
    }
    if (lane == 63 && h < WPR - 1) {
        arp = *(const float4*)(rowI + SEG);
        brp = *(const float4*)(rowJ + SEG);
    }

    // Interior halos: left = lane-1's last chunk, right = lane+1's first chunk.
    float4 al, ar, bl, br;
    al.x = __shfl_up(a1.x, 1, 64); al.y = __shfl_up(a1.y, 1, 64);
    al.z = __shfl_up(a1.z, 1, 64); al.w = __shfl_up(a1.w, 1, 64);
    bl.x = __shfl_up(b1.x, 1, 64); bl.y = __shfl_up(b1.y, 1, 64);
    bl.z = __shfl_up(b1.z, 1, 64); bl.w = __shfl_up(b1.w, 1, 64);
    ar.x = __shfl_down(a0.x, 1, 64); ar.y = __shfl_down(a0.y, 1, 64);
    ar.z = __shfl_down(a0.z, 1, 64); ar.w = __shfl_down(a0.w, 1, 64);
    br.x = __shfl_down(b0.x, 1, 64); br.y = __shfl_down(b0.y, 1, 64);
    br.z = __shfl_down(b0.z, 1, 64); br.w = __shfl_down(b0.w, 1, 64);
    if (lane == 0)  { al = alp; bl = blp; }
    if (lane == 63) { ar = arp; br = brp; }

    // Window array: a[0..3]=left halo, a[4..11]=own, a[12..15]=right halo.
    float a[16], b[16];
    a[0]=al.x; a[1]=al.y; a[2]=al.z; a[3]=al.w;
    a[4]=a0.x; a[5]=a0.y; a[6]=a0.z; a[7]=a0.w;
    a[8]=a1.x; a[9]=a1.y; a[10]=a1.z; a[11]=a1.w;
    a[12]=ar.x; a[13]=ar.y; a[14]=ar.z; a[15]=ar.w;
    b[0]=bl.x; b[1]=bl.y; b[2]=bl.z; b[3]=bl.w;
    b[4]=b0.x; b[5]=b0.y; b[6]=b0.z; b[7]=b0.w;
    b[8]=b1.x; b[9]=b1.y; b[10]=b1.z; b[11]=b1.w;
    b[12]=br.x; b[13]=br.y; b[14]=br.z; b[15]=br.w;

    // 5 sliding sums, init over taps 0..8 (first pixel), then slide.
    float sAc = 0.f, sBc = 0.f, sAA = 0.f, sBB = 0.f, sAB = 0.f;
#pragma unroll
    for (int k = 0; k < 9; ++k) {
        sAc += a[k];
        sBc += b[k];
        sAA = fmaf(a[k], a[k], sAA);
        sBB = fmaf(b[k], b[k], sBB);
        sAB = fmaf(a[k], b[k], sAB);
    }

    const float ninv = -(1.f / 9.f);
    float acc = 0.f;
#pragma unroll
    for (int p = 0; p < PX; ++p) {
        // cross = IJ_sum - I_sum*J_sum/9 ; var = X2_sum - X_sum^2/9
        const float cross = fmaf(sAc * sBc, ninv, sAB);
        const float varA  = fmaf(sAc * sAc, ninv, sAA);
        const float varB  = fmaf(sBc * sBc, ninv, sBB);
        const float denom = fmaf(varA, varB, EPSF);
        acc += (cross * cross) * __builtin_amdgcn_rcpf(denom);
        if (p < PX - 1) {
            const float an = a[9 + p], ao = a[p];
            const float bn = b[9 + p], bo = b[p];
            sAc += an - ao;
            sBc += bn - bo;
            sAA = fmaf(an, an, sAA); sAA = fmaf(ao, -ao, sAA);
            sBB = fmaf(bn, bn, sBB); sBB = fmaf(bo, -bo, sBB);
            sAB = fmaf(an, bn, sAB); sAB = fmaf(ao, -bo, sAB);
        }
    }

    // Deterministic wave reduction (fixed shuffle order), one partial per wave.
#pragma unroll
    for (int off = 32; off > 0; off >>= 1)
        acc += __shfl_down(acc, off, 64);
    if (lane == 0) partials[wid] = acc;
}

// Deterministic sum of 32768 partials (double accum), final transform.
__global__ __launch_bounds__(256) void lncc_finalize(const float* __restrict__ partials,
                                                     float* __restrict__ out) {
    __shared__ double sh[256];
    const int t = threadIdx.x;
    double s = 0.0;
    for (int i = t; i < NWAVES; i += 256)
        s += (double)partials[i];
    sh[t] = s;
    __syncthreads();
    if (t == 0) {
        double tot = 0.0;
        for (int i = 0; i < 256; ++i) tot += sh[i];
        out[0] = (float)(1.0 - tot / NPIX);
    }
}

extern "C" void kernel_launch(void* const* d_in, const int* in_sizes, int n_in,
                              void* d_out, int out_size, void* d_ws, size_t ws_size,
                              hipStream_t stream) {
    const float* I = (const float*)d_in[0];
    const float* J = (const float*)d_in[1];
    float* partials = (float*)d_ws;          // 32768 floats = 128 KiB scratch
    float* out      = (float*)d_out;

    lncc_rows<<<NBLOCKS, 256, 0, stream>>>(I, J, partials);
    lncc_finalize<<<1, 256, 0, stream>>>(partials, out);
}

// Round 3
// 29.650 us; speedup vs baseline: 1.9433x; 1.9433x over previous
//
#include <hip/hip_runtime.h>

#define W      1024
#define NROWS  16384            // 16 * 1 * 1024  (one wave per row)
#define NPIX   16777216.0       // 16 * 1024 * 1024
#define EPSF   1e-5f
#define PX     16               // pixels per lane: 64 lanes * 16 = 1024 = full row
#define NBLOCKS (NROWS / 4)     // 4096 blocks of 4 waves

// One wave per full 1024-px row. No LDS, no barriers, no edge patch loads:
// halo = lane shuffles, zeros at row ends. 8 float4 loads/lane issued upfront.
__global__ __launch_bounds__(256, 4) void lncc_rows(const float* __restrict__ I,
                                                    const float* __restrict__ J,
                                                    float* __restrict__ partials) {
    const int lane = threadIdx.x & 63;
    const int wid  = (blockIdx.x << 2) | (threadIdx.x >> 6);   // == row index
    const size_t base = (size_t)wid * W + lane * PX;

    // 8 independent coalesced float4 loads, all issued before any consumer.
    const float4 A0 = *(const float4*)(I + base);
    const float4 A1 = *(const float4*)(I + base + 4);
    const float4 A2 = *(const float4*)(I + base + 8);
    const float4 A3 = *(const float4*)(I + base + 12);
    const float4 B0 = *(const float4*)(J + base);
    const float4 B1 = *(const float4*)(J + base + 4);
    const float4 B2 = *(const float4*)(J + base + 8);
    const float4 B3 = *(const float4*)(J + base + 12);

    // Halos: left = lane-1's last chunk (zeros for lane 0 = row start),
    //        right = lane+1's first chunk (zeros for lane 63 = row end).
    float4 AL, AR, BL, BR;
    AL.x = __shfl_up(A3.x, 1, 64); AL.y = __shfl_up(A3.y, 1, 64);
    AL.z = __shfl_up(A3.z, 1, 64); AL.w = __shfl_up(A3.w, 1, 64);
    BL.x = __shfl_up(B3.x, 1, 64); BL.y = __shfl_up(B3.y, 1, 64);
    BL.z = __shfl_up(B3.z, 1, 64); BL.w = __shfl_up(B3.w, 1, 64);
    AR.x = __shfl_down(A0.x, 1, 64); AR.y = __shfl_down(A0.y, 1, 64);
    AR.z = __shfl_down(A0.z, 1, 64); AR.w = __shfl_down(A0.w, 1, 64);
    BR.x = __shfl_down(B0.x, 1, 64); BR.y = __shfl_down(B0.y, 1, 64);
    BR.z = __shfl_down(B0.z, 1, 64); BR.w = __shfl_down(B0.w, 1, 64);
    if (lane == 0)  { AL = make_float4(0.f,0.f,0.f,0.f); BL = make_float4(0.f,0.f,0.f,0.f); }
    if (lane == 63) { AR = make_float4(0.f,0.f,0.f,0.f); BR = make_float4(0.f,0.f,0.f,0.f); }

    // Window arrays: [0..3]=left halo, [4..19]=own 16, [20..23]=right halo.
    float a[24], b[24];
    a[0]=AL.x; a[1]=AL.y; a[2]=AL.z; a[3]=AL.w;
    a[4]=A0.x; a[5]=A0.y; a[6]=A0.z; a[7]=A0.w;
    a[8]=A1.x; a[9]=A1.y; a[10]=A1.z; a[11]=A1.w;
    a[12]=A2.x; a[13]=A2.y; a[14]=A2.z; a[15]=A2.w;
    a[16]=A3.x; a[17]=A3.y; a[18]=A3.z; a[19]=A3.w;
    a[20]=AR.x; a[21]=AR.y; a[22]=AR.z; a[23]=AR.w;
    b[0]=BL.x; b[1]=BL.y; b[2]=BL.z; b[3]=BL.w;
    b[4]=B0.x; b[5]=B0.y; b[6]=B0.z; b[7]=B0.w;
    b[8]=B1.x; b[9]=B1.y; b[10]=B1.z; b[11]=B1.w;
    b[12]=B2.x; b[13]=B2.y; b[14]=B2.z; b[15]=B2.w;
    b[16]=B3.x; b[17]=B3.y; b[18]=B3.z; b[19]=B3.w;
    b[20]=BR.x; b[21]=BR.y; b[22]=BR.z; b[23]=BR.w;

    // 5 sliding sums, init over taps 0..8 (first pixel), then slide 15 times.
    float sAc = 0.f, sBc = 0.f, sAA = 0.f, sBB = 0.f, sAB = 0.f;
#pragma unroll
    for (int k = 0; k < 9; ++k) {
        sAc += a[k];
        sBc += b[k];
        sAA = fmaf(a[k], a[k], sAA);
        sBB = fmaf(b[k], b[k], sBB);
        sAB = fmaf(a[k], b[k], sAB);
    }

    const float ninv = -(1.f / 9.f);
    float acc = 0.f;
#pragma unroll
    for (int p = 0; p < PX; ++p) {
        // cross = IJ_sum - I_sum*J_sum/9 ; var = X2_sum - X_sum^2/9
        const float cross = fmaf(sAc * sBc, ninv, sAB);
        const float varA  = fmaf(sAc * sAc, ninv, sAA);
        const float varB  = fmaf(sBc * sBc, ninv, sBB);
        const float denom = fmaf(varA, varB, EPSF);
        acc += (cross * cross) * __builtin_amdgcn_rcpf(denom);
        if (p < PX - 1) {
            const float an = a[9 + p], ao = a[p];
            const float bn = b[9 + p], bo = b[p];
            sAc += an - ao;
            sBc += bn - bo;
            sAA = fmaf(an, an, sAA); sAA = fmaf(ao, -ao, sAA);
            sBB = fmaf(bn, bn, sBB); sBB = fmaf(bo, -bo, sBB);
            sAB = fmaf(an, bn, sAB); sAB = fmaf(ao, -bo, sAB);
        }
    }

    // Deterministic wave reduction (fixed shuffle order), one partial per wave.
#pragma unroll
    for (int off = 32; off > 0; off >>= 1)
        acc += __shfl_down(acc, off, 64);
    if (lane == 0) partials[wid] = acc;
}

// Parallel deterministic finalize: 256 threads x 64 partials each (float4,
// fully unrolled -> independent loads), double accum, fixed-order tree.
__global__ __launch_bounds__(256) void lncc_finalize(const float* __restrict__ partials,
                                                     float* __restrict__ out) {
    __shared__ double sh[256];
    const int t = threadIdx.x;
    double s = 0.0;
#pragma unroll
    for (int c = 0; c < 16; ++c) {
        const float4 v = *(const float4*)(partials + (size_t)t * 64 + c * 4);
        s += ((double)v.x + (double)v.y) + ((double)v.z + (double)v.w);
    }
    sh[t] = s;
    __syncthreads();
    if (t == 0) {
        double tot = 0.0;
        for (int i = 0; i < 256; ++i) tot += sh[i];
        out[0] = (float)(1.0 - tot / NPIX);
    }
}

extern "C" void kernel_launch(void* const* d_in, const int* in_sizes, int n_in,
                              void* d_out, int out_size, void* d_ws, size_t ws_size,
                              hipStream_t stream) {
    const float* I = (const float*)d_in[0];
    const float* J = (const float*)d_in[1];
    float* partials = (float*)d_ws;          // 16384 floats = 64 KiB scratch
    float* out      = (float*)d_out;

    lncc_rows<<<NBLOCKS, 256, 0, stream>>>(I, J, partials);
    lncc_finalize<<<1, 256, 0, stream>>>(partials, out);
}

// Round 4
// 28.759 us; speedup vs baseline: 2.0035x; 1.0310x over previous
//
#include <hip/hip_runtime.h>

#define W      1024
#define NROWS  16384            // 16 * 1 * 1024
#define NPIX   16777216.0       // 16 * 1024 * 1024
#define EPSF   1e-5f
#define PX     16               // pixels per lane: 64 lanes * 16 = full row
#define RPW    2                // rows per wave (pipelined)
#define NWAVES (NROWS / RPW)    // 8192
#define NBLOCKS (NWAVES / 4)    // 2048 blocks of 4 waves

struct Quad { float4 q0, q1, q2, q3; };

// Compute one row's cc partial from its 8 preloaded float4s (own 16 px/lane).
// Halo via lane shuffles; zeros at row ends. Returns per-lane cc sum.
__device__ __forceinline__ float row_cc(const Quad& A, const Quad& B, int lane) {
    float4 AL, AR, BL, BR;
    AL.x = __shfl_up(A.q3.x, 1, 64); AL.y = __shfl_up(A.q3.y, 1, 64);
    AL.z = __shfl_up(A.q3.z, 1, 64); AL.w = __shfl_up(A.q3.w, 1, 64);
    BL.x = __shfl_up(B.q3.x, 1, 64); BL.y = __shfl_up(B.q3.y, 1, 64);
    BL.z = __shfl_up(B.q3.z, 1, 64); BL.w = __shfl_up(B.q3.w, 1, 64);
    AR.x = __shfl_down(A.q0.x, 1, 64); AR.y = __shfl_down(A.q0.y, 1, 64);
    AR.z = __shfl_down(A.q0.z, 1, 64); AR.w = __shfl_down(A.q0.w, 1, 64);
    BR.x = __shfl_down(B.q0.x, 1, 64); BR.y = __shfl_down(B.q0.y, 1, 64);
    BR.z = __shfl_down(B.q0.z, 1, 64); BR.w = __shfl_down(B.q0.w, 1, 64);
    if (lane == 0)  { AL = make_float4(0.f,0.f,0.f,0.f); BL = make_float4(0.f,0.f,0.f,0.f); }
    if (lane == 63) { AR = make_float4(0.f,0.f,0.f,0.f); BR = make_float4(0.f,0.f,0.f,0.f); }

    float a[24], b[24];
    a[0]=AL.x; a[1]=AL.y; a[2]=AL.z; a[3]=AL.w;
    a[4]=A.q0.x; a[5]=A.q0.y; a[6]=A.q0.z; a[7]=A.q0.w;
    a[8]=A.q1.x; a[9]=A.q1.y; a[10]=A.q1.z; a[11]=A.q1.w;
    a[12]=A.q2.x; a[13]=A.q2.y; a[14]=A.q2.z; a[15]=A.q2.w;
    a[16]=A.q3.x; a[17]=A.q3.y; a[18]=A.q3.z; a[19]=A.q3.w;
    a[20]=AR.x; a[21]=AR.y; a[22]=AR.z; a[23]=AR.w;
    b[0]=BL.x; b[1]=BL.y; b[2]=BL.z; b[3]=BL.w;
    b[4]=B.q0.x; b[5]=B.q0.y; b[6]=B.q0.z; b[7]=B.q0.w;
    b[8]=B.q1.x; b[9]=B.q1.y; b[10]=B.q1.z; b[11]=B.q1.w;
    b[12]=B.q2.x; b[13]=B.q2.y; b[14]=B.q2.z; b[15]=B.q2.w;
    b[16]=B.q3.x; b[17]=B.q3.y; b[18]=B.q3.z; b[19]=B.q3.w;
    b[20]=BR.x; b[21]=BR.y; b[22]=BR.z; b[23]=BR.w;

    float sAc = 0.f, sBc = 0.f, sAA = 0.f, sBB = 0.f, sAB = 0.f;
#pragma unroll
    for (int k = 0; k < 9; ++k) {
        sAc += a[k];
        sBc += b[k];
        sAA = fmaf(a[k], a[k], sAA);
        sBB = fmaf(b[k], b[k], sBB);
        sAB = fmaf(a[k], b[k], sAB);
    }

    const float ninv = -(1.f / 9.f);
    float acc = 0.f;
#pragma unroll
    for (int p = 0; p < PX; ++p) {
        const float cross = fmaf(sAc * sBc, ninv, sAB);
        const float varA  = fmaf(sAc * sAc, ninv, sAA);
        const float varB  = fmaf(sBc * sBc, ninv, sBB);
        const float denom = fmaf(varA, varB, EPSF);
        acc += (cross * cross) * __builtin_amdgcn_rcpf(denom);
        if (p < PX - 1) {
            const float an = a[9 + p], ao = a[p];
            const float bn = b[9 + p], bo = b[p];
            sAc += an - ao;
            sBc += bn - bo;
            sAA = fmaf(an, an, sAA); sAA = fmaf(ao, -ao, sAA);
            sBB = fmaf(bn, bn, sBB); sBB = fmaf(bo, -bo, sBB);
            sAB = fmaf(an, bn, sAB); sAB = fmaf(ao, -bo, sAB);
        }
    }
    return acc;
}

// One wave per 2 rows. All 16 float4 loads issued before any consumer:
// row 1's 8 loads stay in flight under row 0's compute (compiler emits
// vmcnt(8) before row-0 use). No LDS, no barriers in the hot path.
__global__ __launch_bounds__(256, 4) void lncc_rows(const float* __restrict__ I,
                                                    const float* __restrict__ J,
                                                    float* __restrict__ partials) {
    const int lane = threadIdx.x & 63;
    const int wid  = (blockIdx.x << 2) | (threadIdx.x >> 6);
    const size_t base0 = (size_t)(2 * wid)     * W + lane * PX;
    const size_t base1 = (size_t)(2 * wid + 1) * W + lane * PX;

    Quad A0, B0, A1, B1;
    A0.q0 = *(const float4*)(I + base0);
    A0.q1 = *(const float4*)(I + base0 + 4);
    A0.q2 = *(const float4*)(I + base0 + 8);
    A0.q3 = *(const float4*)(I + base0 + 12);
    B0.q0 = *(const float4*)(J + base0);
    B0.q1 = *(const float4*)(J + base0 + 4);
    B0.q2 = *(const float4*)(J + base0 + 8);
    B0.q3 = *(const float4*)(J + base0 + 12);
    A1.q0 = *(const float4*)(I + base1);
    A1.q1 = *(const float4*)(I + base1 + 4);
    A1.q2 = *(const float4*)(I + base1 + 8);
    A1.q3 = *(const float4*)(I + base1 + 12);
    B1.q0 = *(const float4*)(J + base1);
    B1.q1 = *(const float4*)(J + base1 + 4);
    B1.q2 = *(const float4*)(J + base1 + 8);
    B1.q3 = *(const float4*)(J + base1 + 12);

    float acc = row_cc(A0, B0, lane);
    acc     += row_cc(A1, B1, lane);

    // Deterministic wave reduction, one partial per wave.
#pragma unroll
    for (int off = 32; off > 0; off >>= 1)
        acc += __shfl_down(acc, off, 64);
    if (lane == 0) partials[wid] = acc;
}

// Deterministic finalize: 256 threads x 32 partials (8 float4, unrolled),
// double accum, fixed-order LDS tree.
__global__ __launch_bounds__(256) void lncc_finalize(const float* __restrict__ partials,
                                                     float* __restrict__ out) {
    __shared__ double sh[256];
    const int t = threadIdx.x;
    double s = 0.0;
#pragma unroll
    for (int c = 0; c < 8; ++c) {
        const float4 v = *(const float4*)(partials + (size_t)t * 32 + c * 4);
        s += ((double)v.x + (double)v.y) + ((double)v.z + (double)v.w);
    }
    sh[t] = s;
    __syncthreads();
#pragma unroll
    for (int off = 128; off > 0; off >>= 1) {
        if (t < off) sh[t] += sh[t + off];
        __syncthreads();
    }
    if (t == 0) out[0] = (float)(1.0 - sh[0] / NPIX);
}

extern "C" void kernel_launch(void* const* d_in, const int* in_sizes, int n_in,
                              void* d_out, int out_size, void* d_ws, size_t ws_size,
                              hipStream_t stream) {
    const float* I = (const float*)d_in[0];
    const float* J = (const float*)d_in[1];
    float* partials = (float*)d_ws;          // 8192 floats = 32 KiB scratch
    float* out      = (float*)d_out;

    lncc_rows<<<NBLOCKS, 256, 0, stream>>>(I, J, partials);
    lncc_finalize<<<1, 256, 0, stream>>>(partials, out);
}

// Round 5
// 28.237 us; speedup vs baseline: 2.0405x; 1.0185x over previous
//
#include <hip/hip_runtime.h>

#define W      1024
#define NROWS  16384            // 16 * 1 * 1024
#define NPIX   16777216.0       // 16 * 1024 * 1024
#define EPSF   1e-5f
#define PX     16               // pixels per lane: 64 lanes * 16 = full row
#define RPW    2                // rows per wave (pipelined)
#define NWAVES (NROWS / RPW)    // 8192
#define NBLOCKS (NWAVES / 4)    // 2048 blocks of 4 waves

struct Quad { float4 q0, q1, q2, q3; };

// Compute one row's cc partial from its 8 preloaded float4s (own 16 px/lane).
// Halo via lane shuffles; zeros at row ends. Returns per-lane cc sum.
__device__ __forceinline__ float row_cc(const Quad& A, const Quad& B, int lane) {
    float4 AL, AR, BL, BR;
    AL.x = __shfl_up(A.q3.x, 1, 64); AL.y = __shfl_up(A.q3.y, 1, 64);
    AL.z = __shfl_up(A.q3.z, 1, 64); AL.w = __shfl_up(A.q3.w, 1, 64);
    BL.x = __shfl_up(B.q3.x, 1, 64); BL.y = __shfl_up(B.q3.y, 1, 64);
    BL.z = __shfl_up(B.q3.z, 1, 64); BL.w = __shfl_up(B.q3.w, 1, 64);
    AR.x = __shfl_down(A.q0.x, 1, 64); AR.y = __shfl_down(A.q0.y, 1, 64);
    AR.z = __shfl_down(A.q0.z, 1, 64); AR.w = __shfl_down(A.q0.w, 1, 64);
    BR.x = __shfl_down(B.q0.x, 1, 64); BR.y = __shfl_down(B.q0.y, 1, 64);
    BR.z = __shfl_down(B.q0.z, 1, 64); BR.w = __shfl_down(B.q0.w, 1, 64);
    if (lane == 0)  { AL = make_float4(0.f,0.f,0.f,0.f); BL = make_float4(0.f,0.f,0.f,0.f); }
    if (lane == 63) { AR = make_float4(0.f,0.f,0.f,0.f); BR = make_float4(0.f,0.f,0.f,0.f); }

    float a[24], b[24];
    a[0]=AL.x; a[1]=AL.y; a[2]=AL.z; a[3]=AL.w;
    a[4]=A.q0.x; a[5]=A.q0.y; a[6]=A.q0.z; a[7]=A.q0.w;
    a[8]=A.q1.x; a[9]=A.q1.y; a[10]=A.q1.z; a[11]=A.q1.w;
    a[12]=A.q2.x; a[13]=A.q2.y; a[14]=A.q2.z; a[15]=A.q2.w;
    a[16]=A.q3.x; a[17]=A.q3.y; a[18]=A.q3.z; a[19]=A.q3.w;
    a[20]=AR.x; a[21]=AR.y; a[22]=AR.z; a[23]=AR.w;
    b[0]=BL.x; b[1]=BL.y; b[2]=BL.z; b[3]=BL.w;
    b[4]=B.q0.x; b[5]=B.q0.y; b[6]=B.q0.z; b[7]=B.q0.w;
    b[8]=B.q1.x; b[9]=B.q1.y; b[10]=B.q1.z; b[11]=B.q1.w;
    b[12]=B.q2.x; b[13]=B.q2.y; b[14]=B.q2.z; b[15]=B.q2.w;
    b[16]=B.q3.x; b[17]=B.q3.y; b[18]=B.q3.z; b[19]=B.q3.w;
    b[20]=BR.x; b[21]=BR.y; b[22]=BR.z; b[23]=BR.w;

    float sAc = 0.f, sBc = 0.f, sAA = 0.f, sBB = 0.f, sAB = 0.f;
#pragma unroll
    for (int k = 0; k < 9; ++k) {
        sAc += a[k];
        sBc += b[k];
        sAA = fmaf(a[k], a[k], sAA);
        sBB = fmaf(b[k], b[k], sBB);
        sAB = fmaf(a[k], b[k], sAB);
    }

    const float ninv = -(1.f / 9.f);
    float acc = 0.f;
#pragma unroll
    for (int p = 0; p < PX; ++p) {
        const float cross = fmaf(sAc * sBc, ninv, sAB);
        const float varA  = fmaf(sAc * sAc, ninv, sAA);
        const float varB  = fmaf(sBc * sBc, ninv, sBB);
        const float denom = fmaf(varA, varB, EPSF);
        acc += (cross * cross) * __builtin_amdgcn_rcpf(denom);
        if (p < PX - 1) {
            const float an = a[9 + p], ao = a[p];
            const float bn = b[9 + p], bo = b[p];
            sAc += an - ao;
            sBc += bn - bo;
            sAA = fmaf(an, an, sAA); sAA = fmaf(ao, -ao, sAA);
            sBB = fmaf(bn, bn, sBB); sBB = fmaf(bo, -bo, sBB);
            sAB = fmaf(an, bn, sAB); sAB = fmaf(ao, -bo, sAB);
        }
    }
    return acc;
}

// One wave per 2 rows. All 16 float4 loads issued (row0's 8 FIRST), then a
// sched_barrier(0) fence so the compiler cannot sink loads / hoist compute:
// row-0 compute waits only vmcnt(8); row-1's loads fly under row-0 compute.
__global__ __launch_bounds__(256, 4) void lncc_rows(const float* __restrict__ I,
                                                    const float* __restrict__ J,
                                                    float* __restrict__ partials) {
    const int lane = threadIdx.x & 63;
    const int wid  = (blockIdx.x << 2) | (threadIdx.x >> 6);
    const size_t base0 = (size_t)(2 * wid)     * W + lane * PX;
    const size_t base1 = (size_t)(2 * wid + 1) * W + lane * PX;

    Quad A0, B0, A1, B1;
    // Row 0's 8 loads first (they'll be the oldest vmcnt entries)...
    A0.q0 = *(const float4*)(I + base0);
    A0.q1 = *(const float4*)(I + base0 + 4);
    A0.q2 = *(const float4*)(I + base0 + 8);
    A0.q3 = *(const float4*)(I + base0 + 12);
    B0.q0 = *(const float4*)(J + base0);
    B0.q1 = *(const float4*)(J + base0 + 4);
    B0.q2 = *(const float4*)(J + base0 + 8);
    B0.q3 = *(const float4*)(J + base0 + 12);
    // ...then row 1's 8.
    A1.q0 = *(const float4*)(I + base1);
    A1.q1 = *(const float4*)(I + base1 + 4);
    A1.q2 = *(const float4*)(I + base1 + 8);
    A1.q3 = *(const float4*)(I + base1 + 12);
    B1.q0 = *(const float4*)(J + base1);
    B1.q1 = *(const float4*)(J + base1 + 4);
    B1.q2 = *(const float4*)(J + base1 + 8);
    B1.q3 = *(const float4*)(J + base1 + 12);
    __builtin_amdgcn_sched_barrier(0);   // all 16 loads issued above this line

    float acc = row_cc(A0, B0, lane);    // waits vmcnt(8) only
    __builtin_amdgcn_sched_barrier(0);   // keep row-1 compute below row-0's
    acc     += row_cc(A1, B1, lane);

    // Deterministic wave reduction, one partial per wave.
#pragma unroll
    for (int off = 32; off > 0; off >>= 1)
        acc += __shfl_down(acc, off, 64);
    if (lane == 0) partials[wid] = acc;
}

// Deterministic finalize: 256 threads x 32 partials (8 float4, unrolled),
// double accum, fixed-order LDS tree.
__global__ __launch_bounds__(256) void lncc_finalize(const float* __restrict__ partials,
                                                     float* __restrict__ out) {
    __shared__ double sh[256];
    const int t = threadIdx.x;
    double s = 0.0;
#pragma unroll
    for (int c = 0; c < 8; ++c) {
        const float4 v = *(const float4*)(partials + (size_t)t * 32 + c * 4);
        s += ((double)v.x + (double)v.y) + ((double)v.z + (double)v.w);
    }
    sh[t] = s;
    __syncthreads();
#pragma unroll
    for (int off = 128; off > 0; off >>= 1) {
        if (t < off) sh[t] += sh[t + off];
        __syncthreads();
    }
    if (t == 0) out[0] = (float)(1.0 - sh[0] / NPIX);
}

extern "C" void kernel_launch(void* const* d_in, const int* in_sizes, int n_in,
                              void* d_out, int out_size, void* d_ws, size_t ws_size,
                              hipStream_t stream) {
    const float* I = (const float*)d_in[0];
    const float* J = (const float*)d_in[1];
    float* partials = (float*)d_ws;          // 8192 floats = 32 KiB scratch
    float* out      = (float*)d_out;

    lncc_rows<<<NBLOCKS, 256, 0, stream>>>(I, J, partials);
    lncc_finalize<<<1, 256, 0, stream>>>(partials, out);
}